// Round 5
// baseline (240.097 us; speedup 1.0000x reference)
//
#include <hip/hip_runtime.h>
#include <math.h>

// Capsule routing, no u_hat materialization.
// Round 5: k_route phase-1 de-staged — u read DIRECTLY from global (L1/L2-hot,
// 8-way row broadcast), only t lives in LDS (swizzled, conflict-free). Zero
// barriers in the k-loop. Tst/cl LDS union -> 32 KB -> 4 blocks/CU.
// Workspace: t(2MB) + sp(16MB) + sp0(0.5MB) = 18.5 MB.

#define B   64
#define IN  1024
#define ID  256
#define NC  32
#define DC  64

// ---------------------------------------------------------------------------
// sp0[c][b][d] = sum over i-chunk c of u[b][i][d]   (8 chunks of 128 i)
__global__ __launch_bounds__(256) void k_sumu(const float* __restrict__ u,
                                              float* __restrict__ sp0) {
    const int c = blockIdx.x, b = blockIdx.y;
    const int d = threadIdx.x;
    const float* up = u + ((size_t)b * IN + (size_t)c * (IN / 8)) * ID + d;
    float acc = 0.f;
#pragma unroll 8
    for (int i = 0; i < IN / 8; ++i) acc += up[(size_t)i * ID];
    sp0[(c * B + b) * ID + d] = acc;
}

// ---------------------------------------------------------------------------
// Per (b,n): s = (reduced partials); o = W_n s ; then
//   mode 0: s from sp0 (uniform c=1/32), normalize o, t = W_n^T o_norm
//   mode 1: s from sp,                  normalize o, t = W_n^T o_norm
//   mode 2: s from sp, squash(o) -> out
__global__ __launch_bounds__(256) void k_ot(const float* __restrict__ W,
                                            const float* __restrict__ src,
                                            float* __restrict__ tout,
                                            const int mode) {
    const int bn = blockIdx.x;
    const int b = bn / NC, n = bn % NC;
    __shared__ float s_lds[ID];
    __shared__ float o_lds[DC];
    __shared__ float on_lds[DC];
    const int tid = threadIdx.x;

    float sv = 0.f;
    if (mode == 0) {
#pragma unroll
        for (int c = 0; c < 8; ++c) sv += src[(c * B + b) * ID + tid];
        sv *= (1.0f / NC);
    } else {
#pragma unroll
        for (int c = 0; c < 8; ++c) sv += src[((size_t)(c * B + b) * NC + n) * ID + tid];
    }
    s_lds[tid] = sv;
    __syncthreads();

    const int wave = tid >> 6, lane = tid & 63;
    const float* Wn = W + (size_t)n * DC * ID;
#pragma unroll 4
    for (int r = 0; r < 16; ++r) {
        const int d = wave * 16 + r;
        const float* wrow = Wn + (size_t)d * ID;
        float p = wrow[lane]        * s_lds[lane]
                + wrow[lane + 64]   * s_lds[lane + 64]
                + wrow[lane + 128]  * s_lds[lane + 128]
                + wrow[lane + 192]  * s_lds[lane + 192];
#pragma unroll
        for (int off = 32; off > 0; off >>= 1) p += __shfl_down(p, off);
        if (lane == 0) o_lds[d] = p;
    }
    __syncthreads();

    if (mode == 2) {
        if (tid < DC) {
            float v = o_lds[tid];
            float sq = v * v;
#pragma unroll
            for (int off = 32; off > 0; off >>= 1) sq += __shfl_down(sq, off);
            sq = __shfl(sq, 0) + 1e-7f;
            const float sc = sqrtf(sq) / (0.5f + sq);
            tout[(size_t)(b * NC + n) * DC + tid] = v * sc;
        }
        return;
    }

    if (tid < DC) {
        float v = o_lds[tid];
        float sq = v * v;
#pragma unroll
        for (int off = 32; off > 0; off >>= 1) sq += __shfl_down(sq, off);
        sq = __shfl(sq, 0);
        const float inv = 1.0f / fmaxf(sqrtf(sq), 1e-12f);
        on_lds[tid] = v * inv;
    }
    __syncthreads();

    float acc = 0.f;
    const float* wc = Wn + tid;
#pragma unroll 8
    for (int d = 0; d < DC; ++d) acc += wc[(size_t)d * ID] * on_lds[d];
    tout[((size_t)b * NC + n) * ID + tid] = acc;
}

// ---------------------------------------------------------------------------
// Fused routing step. Block: (i-tile of 128, b), 256 threads, LDS 32 KB.
//   phase 1: logits[i][n] = u[i,:].t[n,:] — u direct from global (no staging,
//            no in-loop barriers), t LDS-resident swizzled.
//   phase 2: softmax over n (cl overlays Tst — Tst dead after phase 1)
//   phase 3: sp[it][b][n][d] = sum_i c[i][n] u[i][d]  (u re-read, L2-hot)
#define RTILE 128
__global__ __launch_bounds__(256, 4) void k_route(const float* __restrict__ u,
                                                  const float* __restrict__ t,
                                                  float* __restrict__ sp) {
    const int it = blockIdx.x, b = blockIdx.y;
    const int iBase = it * RTILE;
    __shared__ __align__(16) float smem[NC * ID];   // 32 KB, dual-purpose
    float (*Tst)[ID] = (float(*)[ID])smem;          // phase 1: t swizzled
    float (*cl)[36]  = (float(*)[36])smem;          // phase 2/3: coeffs (18 KB)
    const int tid = threadIdx.x;

    const float* ub = u + ((size_t)b * IN + iBase) * ID;
    const float* tb = t + (size_t)b * NC * ID;

    // ---- stage Tst once: rows col-swizzled by ((n>>2)<<2) for conflict-free
    //      8-row b128 column reads in phase 1 ----
#pragma unroll
    for (int rep = 0; rep < 8; ++rep) {
        const int idx = tid + rep * 256;          // 2048 f4 total
        const int n = idx >> 6, c4 = idx & 63;
        const float4 v = *(const float4*)(tb + (size_t)n * ID + c4 * 4);
        *(float4*)&Tst[n][(c4 * 4) ^ ((n >> 2) << 2)] = v;
    }
    __syncthreads();

    // ---- phase 1: logits, zero in-loop barriers ----
    const int q = tid >> 3;   // i-group: i0 = q*4   (32 groups)
    const int r = tid & 7;    // n-group: n0 = r*4   (8 groups)
    const int i0 = q * 4, n0 = r * 4;
    const int rsw = r << 2;   // == (n>>2)<<2 for n in [n0, n0+3]
    float acc[4][4] = {{0.f}};
    const float* up0 = ub + (size_t)(i0 + 0) * ID;
    const float* up1 = ub + (size_t)(i0 + 1) * ID;
    const float* up2 = ub + (size_t)(i0 + 2) * ID;
    const float* up3 = ub + (size_t)(i0 + 3) * ID;

#pragma unroll 4
    for (int k4 = 0; k4 < ID / 4; ++k4) {
        float4 a[4];
        a[0] = *(const float4*)(up0 + k4 * 4);
        a[1] = *(const float4*)(up1 + k4 * 4);
        a[2] = *(const float4*)(up2 + k4 * 4);
        a[3] = *(const float4*)(up3 + k4 * 4);
        const int bc = (k4 * 4) ^ rsw;
        float4 bv[4];
#pragma unroll
        for (int jj = 0; jj < 4; ++jj) bv[jj] = *(const float4*)&Tst[n0 + jj][bc];
#pragma unroll
        for (int ii = 0; ii < 4; ++ii)
#pragma unroll
            for (int jj = 0; jj < 4; ++jj)
                acc[ii][jj] += a[ii].x * bv[jj].x + a[ii].y * bv[jj].y
                             + a[ii].z * bv[jj].z + a[ii].w * bv[jj].w;
    }
    __syncthreads();   // Tst dead everywhere; smem region may be reused as cl

    // logits -> cl
#pragma unroll
    for (int ii = 0; ii < 4; ++ii)
        *(float4*)&cl[i0 + ii][n0] =
            make_float4(acc[ii][0], acc[ii][1], acc[ii][2], acc[ii][3]);
    __syncthreads();

    // ---- phase 2: softmax over 32 n; 2 threads per i (16 n each) ----
    {
        const int i = tid >> 1, half = tid & 1;
        float v[16];
#pragma unroll
        for (int j = 0; j < 16; ++j) v[j] = cl[i][half * 16 + j];
        float mx = v[0];
#pragma unroll
        for (int j = 1; j < 16; ++j) mx = fmaxf(mx, v[j]);
        mx = fmaxf(mx, __shfl_xor(mx, 1));
        float sum = 0.f;
#pragma unroll
        for (int j = 0; j < 16; ++j) { v[j] = __expf(v[j] - mx); sum += v[j]; }
        sum += __shfl_xor(sum, 1);
        const float inv = 1.0f / sum;
#pragma unroll
        for (int j = 0; j < 16; ++j) cl[i][half * 16 + j] = v[j] * inv;
    }
    __syncthreads();

    // ---- phase 3: weighted aggregation (u tile re-read, L2-hot) ----
    const int d4 = tid & 63;       // float4 index into ID
    const int ng = tid >> 6;       // n base = ng*8 (wave-uniform -> LDS broadcast)
    float a2[8][4] = {{0.f}};
    const float* ur = ub + d4 * 4;
#pragma unroll 4
    for (int i = 0; i < RTILE; ++i) {
        const float4 uv = *(const float4*)(ur + (size_t)i * ID);
        const float4 c0 = *(const float4*)&cl[i][ng * 8];
        const float4 c1 = *(const float4*)&cl[i][ng * 8 + 4];
        const float cv[8] = {c0.x, c0.y, c0.z, c0.w, c1.x, c1.y, c1.z, c1.w};
        const float uvv[4] = {uv.x, uv.y, uv.z, uv.w};
#pragma unroll
        for (int j = 0; j < 8; ++j)
#pragma unroll
            for (int x = 0; x < 4; ++x) a2[j][x] += cv[j] * uvv[x];
    }

    float* spb = sp + (size_t)(it * B + b) * NC * ID;
#pragma unroll
    for (int j = 0; j < 8; ++j) {
        const int n = ng * 8 + j;
        *(float4*)&spb[(size_t)n * ID + d4 * 4] =
            make_float4(a2[j][0], a2[j][1], a2[j][2], a2[j][3]);
    }
}

// ---------------------------------------------------------------------------
extern "C" void kernel_launch(void* const* d_in, const int* in_sizes, int n_in,
                              void* d_out, int out_size, void* d_ws, size_t ws_size,
                              hipStream_t stream) {
    const float* u = (const float*)d_in[0];   // [B][IN][ID]
    const float* W = (const float*)d_in[1];   // [NC*DC][ID]
    float* out = (float*)d_out;               // [B][NC][DC]

    float* ws  = (float*)d_ws;
    float* t   = ws;                                   // B*NC*ID      = 0.5M floats
    float* sp  = t + (size_t)B * NC * ID;              // 8*B*NC*ID    = 4M floats
    float* sp0 = sp + (size_t)8 * B * NC * ID;         // 8*B*ID       = 128K floats

    // routing iteration 0 (c uniform = 1/32)
    k_sumu <<<dim3(8, B), dim3(256), 0, stream>>>(u, sp0);
    k_ot   <<<dim3(B * NC), dim3(256), 0, stream>>>(W, sp0, t, 0);
    // iteration 1 (logits + softmax + aggregate fused)
    k_route<<<dim3(IN / RTILE, B), dim3(256), 0, stream>>>(u, t, sp);
    k_ot   <<<dim3(B * NC), dim3(256), 0, stream>>>(W, sp, t, 1);
    // iteration 2
    k_route<<<dim3(IN / RTILE, B), dim3(256), 0, stream>>>(u, t, sp);
    k_ot   <<<dim3(B * NC), dim3(256), 0, stream>>>(W, sp, out, 2);
}

// Round 7
// 239.077 us; speedup vs baseline: 1.0043x; 1.0043x over previous
//
#include <hip/hip_runtime.h>
#include <math.h>

// Capsule routing, no u_hat materialization.
// Round 7: occupancy lever retried SAFELY — 512-thread blocks, RTILE=128,
// sp stays at 8 chunks (workspace 18.5 MB, the proven envelope; R6's 34.5 MB
// may have overflowed ws and killed the container). Tst swizzled once (R5),
// u staged i-major f4 (1 ld + 1 st per thread/chunk), R2 barrier skeleton,
// acc[4][4] with k-split-2 + shfl_xor reduce. LDS 50.4 KB -> 16 waves/CU.

#define B   64
#define IN  1024
#define ID  256
#define NC  32
#define DC  64

// ---------------------------------------------------------------------------
// sp0[c][b][d] = sum over i-chunk c of u[b][i][d]   (8 chunks of 128 i)
__global__ __launch_bounds__(256) void k_sumu(const float* __restrict__ u,
                                              float* __restrict__ sp0) {
    const int c = blockIdx.x, b = blockIdx.y;
    const int d = threadIdx.x;
    const float* up = u + ((size_t)b * IN + (size_t)c * (IN / 8)) * ID + d;
    float acc = 0.f;
#pragma unroll 8
    for (int i = 0; i < IN / 8; ++i) acc += up[(size_t)i * ID];
    sp0[(c * B + b) * ID + d] = acc;
}

// ---------------------------------------------------------------------------
// Per (b,n): s = (reduced partials); o = W_n s ; then
//   mode 0: s from sp0 (uniform c=1/32), normalize o, t = W_n^T o_norm
//   mode 1: s from sp,                  normalize o, t = W_n^T o_norm
//   mode 2: s from sp, squash(o) -> out
__global__ __launch_bounds__(256) void k_ot(const float* __restrict__ W,
                                            const float* __restrict__ src,
                                            float* __restrict__ tout,
                                            const int mode) {
    const int bn = blockIdx.x;
    const int b = bn / NC, n = bn % NC;
    __shared__ float s_lds[ID];
    __shared__ float o_lds[DC];
    __shared__ float on_lds[DC];
    const int tid = threadIdx.x;

    float sv = 0.f;
    if (mode == 0) {
#pragma unroll
        for (int c = 0; c < 8; ++c) sv += src[(c * B + b) * ID + tid];
        sv *= (1.0f / NC);
    } else {
#pragma unroll
        for (int c = 0; c < 8; ++c) sv += src[((size_t)(c * B + b) * NC + n) * ID + tid];
    }
    s_lds[tid] = sv;
    __syncthreads();

    const int wave = tid >> 6, lane = tid & 63;
    const float* Wn = W + (size_t)n * DC * ID;
#pragma unroll 4
    for (int r = 0; r < 16; ++r) {
        const int d = wave * 16 + r;
        const float* wrow = Wn + (size_t)d * ID;
        float p = wrow[lane]        * s_lds[lane]
                + wrow[lane + 64]   * s_lds[lane + 64]
                + wrow[lane + 128]  * s_lds[lane + 128]
                + wrow[lane + 192]  * s_lds[lane + 192];
#pragma unroll
        for (int off = 32; off > 0; off >>= 1) p += __shfl_down(p, off);
        if (lane == 0) o_lds[d] = p;
    }
    __syncthreads();

    if (mode == 2) {
        if (tid < DC) {
            float v = o_lds[tid];
            float sq = v * v;
#pragma unroll
            for (int off = 32; off > 0; off >>= 1) sq += __shfl_down(sq, off);
            sq = __shfl(sq, 0) + 1e-7f;
            const float sc = sqrtf(sq) / (0.5f + sq);
            tout[(size_t)(b * NC + n) * DC + tid] = v * sc;
        }
        return;
    }

    if (tid < DC) {
        float v = o_lds[tid];
        float sq = v * v;
#pragma unroll
        for (int off = 32; off > 0; off >>= 1) sq += __shfl_down(sq, off);
        sq = __shfl(sq, 0);
        const float inv = 1.0f / fmaxf(sqrtf(sq), 1e-12f);
        on_lds[tid] = v * inv;
    }
    __syncthreads();

    float acc = 0.f;
    const float* wc = Wn + tid;
#pragma unroll 8
    for (int d = 0; d < DC; ++d) acc += wc[(size_t)d * ID] * on_lds[d];
    tout[((size_t)b * NC + n) * ID + tid] = acc;
}

// ---------------------------------------------------------------------------
// Fused routing step. Block: (i-tile of 128, b), 512 threads, LDS 50.4 KB.
//   phase 1: logits[i][n] = u[i,:].t[n,:] — Tst (32KB swizzled, staged once),
//            Us2 staged i-major; thread=(q,r,s): i0=q*4, n0=r*4, k-slice s.
//   shfl_xor(1) reduces k-slices; cl overlays Us2 (barrier-guarded).
//   phase 2: softmax over n ; phase 3: sp[it][b][n][d] = sum_i c[i][n] u[i][d]
#define RTILE 128
__global__ __launch_bounds__(512, 4) void k_route(const float* __restrict__ u,
                                                  const float* __restrict__ t,
                                                  float* __restrict__ sp) {
    const int it = blockIdx.x, b = blockIdx.y;
    const int iBase = it * RTILE;
    __shared__ __align__(16) float Tst[NC][ID];       // 32 KB, phase 1 only
    __shared__ __align__(16) float rest[RTILE * 36];  // 18.4 KB: Us2 then cl
    float (*Us2)[20] = (float(*)[20])rest;            // [128][20] = 10 KB
    float (*cl)[36]  = (float(*)[36])rest;            // [128][36] = 18.4 KB
    const int tid = threadIdx.x;

    const float* ub = u + ((size_t)b * IN + iBase) * ID;
    const float* tb = t + (size_t)b * NC * ID;

    // ---- stage Tst once: natural rows, f4-col swizzled by (n>>2)<<2 ----
#pragma unroll
    for (int rep = 0; rep < 4; ++rep) {
        const int idx = tid + rep * 512;          // 2048 f4
        const int n = idx >> 6, c4 = idx & 63;
        const float4 v = *(const float4*)(tb + (size_t)n * ID + c4 * 4);
        *(float4*)&Tst[n][(c4 * 4) ^ ((n >> 2) << 2)] = v;
    }

    // ---- phase 1 ----
    const int s  = tid & 1;          // k-slice (8 k of each 16-chunk)
    const int r  = (tid >> 1) & 7;   // n-group: n0 = r*4
    const int q  = tid >> 4;         // i-group: i0 = q*4   (32 groups)
    const int i0 = q * 4, n0 = r * 4;
    const int rsw = r << 2;          // == (n>>2)<<2 for n0..n0+3
    // staging map: 512 f4 per chunk, 1 per thread
    const int si = tid >> 2, sc4 = tid & 3;
    float acc[4][4] = {{0.f}};

    for (int kc = 0; kc < ID / 16; ++kc) {
        __syncthreads();   // prior chunk consumed (and Tst ready at kc=0)
        *(float4*)&Us2[si][sc4 * 4] =
            *(const float4*)(ub + (size_t)si * ID + kc * 16 + sc4 * 4);
        __syncthreads();
#pragma unroll
        for (int kk4 = 0; kk4 < 2; ++kk4) {
            const int lk = s * 8 + kk4 * 4;          // local k (f4 base)
            float4 a[4], bv[4];
#pragma unroll
            for (int ii = 0; ii < 4; ++ii) a[ii] = *(const float4*)&Us2[i0 + ii][lk];
            const int bc = (kc * 16 + lk) ^ rsw;
#pragma unroll
            for (int jj = 0; jj < 4; ++jj) bv[jj] = *(const float4*)&Tst[n0 + jj][bc];
#pragma unroll
            for (int ii = 0; ii < 4; ++ii)
#pragma unroll
                for (int jj = 0; jj < 4; ++jj)
                    acc[ii][jj] += a[ii].x * bv[jj].x + a[ii].y * bv[jj].y
                                 + a[ii].z * bv[jj].z + a[ii].w * bv[jj].w;
        }
    }
    // reduce the two k-slices (lanes differ in bit 0)
#pragma unroll
    for (int ii = 0; ii < 4; ++ii)
#pragma unroll
        for (int jj = 0; jj < 4; ++jj)
            acc[ii][jj] += __shfl_xor(acc[ii][jj], 1);

    __syncthreads();   // all Us2/Tst reads done -> safe to overlay cl
    {
        const int iiBase = s * 2;  // s=0 writes rows 0,1 ; s=1 rows 2,3
#pragma unroll
        for (int v = 0; v < 2; ++v) {
            const int ii = iiBase + v;
            *(float4*)&cl[i0 + ii][n0] =
                make_float4(acc[ii][0], acc[ii][1], acc[ii][2], acc[ii][3]);
        }
    }
    __syncthreads();

    // ---- phase 2: softmax over 32 n; 4 threads per i (8 n each) ----
    {
        const int i = tid >> 2, quad = tid & 3;
        float v[8];
#pragma unroll
        for (int j = 0; j < 8; ++j) v[j] = cl[i][quad * 8 + j];
        float mx = v[0];
#pragma unroll
        for (int j = 1; j < 8; ++j) mx = fmaxf(mx, v[j]);
        mx = fmaxf(mx, __shfl_xor(mx, 1));
        mx = fmaxf(mx, __shfl_xor(mx, 2));
        float sum = 0.f;
#pragma unroll
        for (int j = 0; j < 8; ++j) { v[j] = __expf(v[j] - mx); sum += v[j]; }
        sum += __shfl_xor(sum, 1);
        sum += __shfl_xor(sum, 2);
        const float inv = 1.0f / sum;
#pragma unroll
        for (int j = 0; j < 8; ++j) cl[i][quad * 8 + j] = v[j] * inv;
    }
    __syncthreads();

    // ---- phase 3: weighted aggregation (u tile re-read, L2-hot) ----
    const int d4 = tid & 63;       // float4 index into ID
    const int ng = tid >> 6;       // n base = ng*4 (wave-uniform -> LDS broadcast)
    float a2[4][4] = {{0.f}};
    const float* ur = ub + d4 * 4;
#pragma unroll 4
    for (int i = 0; i < RTILE; ++i) {
        const float4 uv = *(const float4*)(ur + (size_t)i * ID);
        const float4 c0 = *(const float4*)&cl[i][ng * 4];
        const float cv[4] = {c0.x, c0.y, c0.z, c0.w};
        const float uvv[4] = {uv.x, uv.y, uv.z, uv.w};
#pragma unroll
        for (int j = 0; j < 4; ++j)
#pragma unroll
            for (int x = 0; x < 4; ++x) a2[j][x] += cv[j] * uvv[x];
    }

    float* spb = sp + (size_t)(it * B + b) * NC * ID;
#pragma unroll
    for (int j = 0; j < 4; ++j) {
        const int n = ng * 4 + j;
        *(float4*)&spb[(size_t)n * ID + d4 * 4] =
            make_float4(a2[j][0], a2[j][1], a2[j][2], a2[j][3]);
    }
}

// ---------------------------------------------------------------------------
extern "C" void kernel_launch(void* const* d_in, const int* in_sizes, int n_in,
                              void* d_out, int out_size, void* d_ws, size_t ws_size,
                              hipStream_t stream) {
    const float* u = (const float*)d_in[0];   // [B][IN][ID]
    const float* W = (const float*)d_in[1];   // [NC*DC][ID]
    float* out = (float*)d_out;               // [B][NC][DC]

    float* ws  = (float*)d_ws;
    float* t   = ws;                                   // B*NC*ID      = 0.5M floats
    float* sp  = t + (size_t)B * NC * ID;              // 8*B*NC*ID    = 4M floats
    float* sp0 = sp + (size_t)8 * B * NC * ID;         // 8*B*ID       = 128K floats

    // routing iteration 0 (c uniform = 1/32)
    k_sumu <<<dim3(8, B), dim3(256), 0, stream>>>(u, sp0);
    k_ot   <<<dim3(B * NC), dim3(256), 0, stream>>>(W, sp0, t, 0);
    // iteration 1 (logits + softmax + aggregate fused)
    k_route<<<dim3(IN / RTILE, B), dim3(512), 0, stream>>>(u, t, sp);
    k_ot   <<<dim3(B * NC), dim3(256), 0, stream>>>(W, sp, t, 1);
    // iteration 2
    k_route<<<dim3(IN / RTILE, B), dim3(512), 0, stream>>>(u, t, sp);
    k_ot   <<<dim3(B * NC), dim3(256), 0, stream>>>(W, sp, out, 2);
}